// Round 12
// baseline (103.565 us; speedup 1.0000x reference)
//
#include <hip/hip_runtime.h>
#include <hip/hip_bf16.h>
#include <math.h>

// BahdanauAttention: B=32, T=2048, D=512, U=512, fp32 in/out.
#define BB 32
#define TT 2048
#define DD 512
#define UU 512

typedef __attribute__((ext_vector_type(8))) short short8v;     // MFMA bf16 A/B frag
typedef __attribute__((ext_vector_type(4))) float floatx4;     // MFMA C/D frag
typedef __attribute__((ext_vector_type(8))) unsigned short ushort8v;
typedef __attribute__((ext_vector_type(4))) unsigned short ushort4v;

static __device__ inline unsigned short f2bf(float f) {
  __hip_bfloat16 h = __float2bfloat16(f);
  return *reinterpret_cast<unsigned short*>(&h);
}

static __device__ inline float fast_tanh(float x) {
  x = fminf(fmaxf(x, -15.f), 15.f);
  float e2 = __expf(2.f * x);
  return (e2 - 1.f) * __builtin_amdgcn_rcpf(e2 + 1.f);
}

// ---------------------------------------------------------------------------
// K0: W1[k][u] fp32 -> w1a blocked bf16 [kt(16)][kg(4)][u(512)][8]:
// chunk (kt,kg,u)[e] = bf16(W1[kt*32+kg*8+e][u]). grid (16 kt, 4 uc).
// ---------------------------------------------------------------------------
__global__ __launch_bounds__(256) void pack_w1a_kernel(
    const float* __restrict__ W1, unsigned short* __restrict__ w1a) {
  __shared__ float Wf[32][132];  // pitch 132 -> col-gather conflict-free
  const int kt = blockIdx.x, uc = blockIdx.y;
  const int tid = threadIdx.x;
  {
    const int k = tid >> 3;
    const int u16 = (tid & 7) * 16;
    const float* src = W1 + (size_t)(kt * 32 + k) * UU + uc * 128 + u16;
    #pragma unroll
    for (int q = 0; q < 4; ++q) {
      const float4 v = *(const float4*)(src + q * 4);
      Wf[k][u16 + q * 4 + 0] = v.x;
      Wf[k][u16 + q * 4 + 1] = v.y;
      Wf[k][u16 + q * 4 + 2] = v.z;
      Wf[k][u16 + q * 4 + 3] = v.w;
    }
  }
  __syncthreads();
  unsigned short* dst = w1a + (size_t)kt * 16384;  // 32 KB per kt
  #pragma unroll
  for (int s = 0; s < 2; ++s) {
    const int c = s * 256 + tid;           // local chunk 0..511
    const int kg = c >> 7;
    const int u = c & 127;
    ushort8v o;
    #pragma unroll
    for (int e = 0; e < 8; ++e) o[e] = f2bf(Wf[kg * 8 + e][u]);
    *(ushort8v*)(dst + ((size_t)kg * 512 + uc * 128 + u) * 8) = o;
  }
}

// ---------------------------------------------------------------------------
// K1: qb[b,u] = query[b,:] @ W2[:,u] + b2[u] + b1[u]
// ---------------------------------------------------------------------------
__global__ __launch_bounds__(256) void projq_kernel(
    const float* __restrict__ query, const float* __restrict__ W2,
    const float* __restrict__ b2, const float* __restrict__ b1,
    float* __restrict__ qb) {
  int b = blockIdx.x;
  int u = blockIdx.y * 256 + threadIdx.x;
  float acc = b2[u] + b1[u];
  const float* q = query + b * DD;
  #pragma unroll 16
  for (int d = 0; d < DD; ++d) acc += q[d] * W2[(size_t)d * UU + u];
  qb[b * UU + u] = acc;
}

// ---------------------------------------------------------------------------
// K2: swapped-operand MFMA score kernel — two-phase pipelined staging +
// distance-2 A-prefetch (ring-3). Race-free class: plain VGPR loads, LDS
// writes ordered only by __syncthreads (3 barriers total).
//   phase 0: stage B half-0 (kt 0..7), barrier, ISSUE half-1 loads,
//            run steps 0..7 (MFMA hides half-1 HBM latency),
//            cvt+write half-1, barrier, run steps 8..15.
//   A(t+2) prefetched during step t from L2/L3-hot w1a (per-wave-private).
// 8 waves; wave = 64u x 64m. LDS ~70 KB -> 2 blocks/CU (VGPR-bound anyway).
// ---------------------------------------------------------------------------
#define SBM 64

__global__ __launch_bounds__(512, 4) void score_kernel(
    const float* __restrict__ values, const unsigned short* __restrict__ w1a,
    const float* __restrict__ qb, const float* __restrict__ V,
    float* __restrict__ score) {
  __shared__ __align__(16) unsigned short Bp[2][8][4][SBM][8];  // 2 x 32 KB
  __shared__ float qv_lds[512];
  __shared__ float vv_lds[512];
  __shared__ float part[8][SBM];

  const int tid = threadIdx.x;
  const int row0 = blockIdx.x * SBM;
  const int b = row0 >> 11;           // row0 / TT
  const int lane = tid & 63;
  const int wid = tid >> 6;           // 8 waves -> u slice
  const int wu = wid * 64;
  const int fr = lane & 15;
  const int kg = lane >> 4;

  qv_lds[tid] = qb[b * UU + tid];     // b1,b2 folded into qb
  vv_lds[tid] = V[tid];

  // staging geometry: thread owns (row sm, k-quad sj); kt-local stride 2048 us
  const int sm = tid >> 3;
  const int sj = tid & 7;
  const float* bsrc = values + (size_t)(row0 + sm) * DD + sj * 4;
  const int bofs = (sj >> 1) * (SBM * 8) + sm * 8 + (sj & 1) * 4;  // in one kt slab

  // ---- stage half-0 (kt 0..7) ----
  {
    float4 r0[8];
    #pragma unroll
    for (int q = 0; q < 8; ++q)
      r0[q] = *(const float4*)(bsrc + (size_t)q * 32);
    #pragma unroll
    for (int q = 0; q < 8; ++q) {
      ushort4v o = {f2bf(r0[q].x), f2bf(r0[q].y), f2bf(r0[q].z), f2bf(r0[q].w)};
      *(ushort4v*)(&Bp[0][q][0][0][0] + bofs) = o;
    }
  }

  // ---- A-frag prefetch ring (distance 2): prologue A(0), A(1) ----
  const size_t aofs = (size_t)(kg * 512 + wu + fr) * 8;
  short8v af[3][4];
  #pragma unroll
  for (int ju = 0; ju < 4; ++ju) {
    af[0][ju] = *(const short8v*)(w1a + aofs + (size_t)ju * 128);
    af[1][ju] = *(const short8v*)(w1a + 16384 + aofs + (size_t)ju * 128);
  }

  __syncthreads();  // barrier 1: half-0 visible

  // ---- issue ALL half-1 loads now; consumed after step 7 (latency hidden) ----
  float4 r1[8];
  #pragma unroll
  for (int q = 0; q < 8; ++q)
    r1[q] = *(const float4*)(bsrc + (size_t)(8 + q) * 32);

  floatx4 acc[4][4] = {};  // [ju][jm]

  #pragma unroll
  for (int t = 0; t < 16; ++t) {
    if (t == 8) {
      // cvt + write half-1 (r1 loaded ~8 MFMA-steps ago), then barrier
      #pragma unroll
      for (int q = 0; q < 8; ++q) {
        ushort4v o = {f2bf(r1[q].x), f2bf(r1[q].y), f2bf(r1[q].z), f2bf(r1[q].w)};
        *(ushort4v*)(&Bp[1][q][0][0][0] + bofs) = o;
      }
      __syncthreads();  // barrier 2: half-1 visible (loop-0 reads done for all)
    }

    // prefetch A(t+2) into ring slot (t+2)%3
    if (t + 2 < 16) {
      #pragma unroll
      for (int ju = 0; ju < 4; ++ju)
        af[(t + 2) % 3][ju] =
            *(const short8v*)(w1a + (size_t)(t + 2) * 16384 + aofs + (size_t)ju * 128);
    }

    // 16 MFMA on step t
    #pragma unroll
    for (int jm = 0; jm < 4; ++jm) {
      const short8v bfv = *(const short8v*)&Bp[t >> 3][t & 7][kg][jm * 16 + fr][0];
      #pragma unroll
      for (int ju = 0; ju < 4; ++ju)
        acc[ju][jm] = __builtin_amdgcn_mfma_f32_16x16x32_bf16(af[t % 3][ju], bfv, acc[ju][jm], 0, 0, 0);
    }
  }

  // ---- epilogue: tanh + V-weight; u on the register axis ----
  // C[u][m]: m = jm*16 + fr, u = wu + ju*16 + kg*4 + reg
  float pm[4] = {0.f, 0.f, 0.f, 0.f};
  #pragma unroll
  for (int ju = 0; ju < 4; ++ju) {
    const float4 qv = *(const float4*)&qv_lds[wu + ju * 16 + kg * 4];
    const float4 vv = *(const float4*)&vv_lds[wu + ju * 16 + kg * 4];
    const float qa[4] = {qv.x, qv.y, qv.z, qv.w};
    const float va[4] = {vv.x, vv.y, vv.z, vv.w};
    #pragma unroll
    for (int jm = 0; jm < 4; ++jm)
      #pragma unroll
      for (int reg = 0; reg < 4; ++reg)
        pm[jm] += fast_tanh(acc[ju][jm][reg] + qa[reg]) * va[reg];
  }
  #pragma unroll
  for (int jm = 0; jm < 4; ++jm) {
    pm[jm] += __shfl_xor(pm[jm], 16, 64);
    pm[jm] += __shfl_xor(pm[jm], 32, 64);
  }
  if (lane < 16) {
    #pragma unroll
    for (int jm = 0; jm < 4; ++jm) part[wid][jm * 16 + lane] = pm[jm];
  }
  __syncthreads();  // barrier 3
  if (tid < SBM) {
    float s = 0.f;
    #pragma unroll
    for (int w = 0; w < 8; ++w) s += part[w][tid];
    score[row0 + tid] = s;
  }
}

// ---------------------------------------------------------------------------
// K3: softmax over T per batch.
// ---------------------------------------------------------------------------
__global__ __launch_bounds__(256) void softmax_kernel(
    const float* __restrict__ score, float* __restrict__ attn) {
  const int b = blockIdx.x;
  const int tid = threadIdx.x;
  __shared__ float red[256];

  float m = -INFINITY;
  for (int t = tid; t < TT; t += 256) m = fmaxf(m, score[b * TT + t]);
  red[tid] = m;
  __syncthreads();
  for (int s = 128; s > 0; s >>= 1) {
    if (tid < s) red[tid] = fmaxf(red[tid], red[tid + s]);
    __syncthreads();
  }
  const float bm = red[0];
  __syncthreads();

  float sum = 0.f;
  for (int t = tid; t < TT; t += 256) sum += __expf(score[b * TT + t] - bm);
  red[tid] = sum;
  __syncthreads();
  for (int s = 128; s > 0; s >>= 1) {
    if (tid < s) red[tid] += red[tid + s];
    __syncthreads();
  }
  const float inv = 1.f / red[0];
  __syncthreads();

  for (int t = tid; t < TT; t += 256)
    attn[b * TT + t] = __expf(score[b * TT + t] - bm) * inv;
}

// ---------------------------------------------------------------------------
// K4a: context partials, NO atomics. grid (64 splits, 32 b), block 128.
// ---------------------------------------------------------------------------
#define CSPLIT 64
__global__ __launch_bounds__(128) void context1_kernel(
    const float* __restrict__ values, const float* __restrict__ attn,
    float* __restrict__ partial) {
  const int s = blockIdx.x;
  const int b = blockIdx.y;
  const int t0 = s * (TT / CSPLIT);
  const int d = threadIdx.x * 4;
  float4 a = {0.f, 0.f, 0.f, 0.f};
  #pragma unroll 4
  for (int t = t0; t < t0 + TT / CSPLIT; ++t) {
    const float w = attn[b * TT + t];
    const float4 v = *(const float4*)(values + (size_t)(b * TT + t) * DD + d);
    a.x += w * v.x; a.y += w * v.y; a.z += w * v.z; a.w += w * v.w;
  }
  *(float4*)(partial + ((size_t)s * BB + b) * DD + d) = a;
}

// ---------------------------------------------------------------------------
// K4b: reduce partials -> ctx. grid (32 b), block 128.
// ---------------------------------------------------------------------------
__global__ __launch_bounds__(128) void context2_kernel(
    const float* __restrict__ partial, float* __restrict__ ctx) {
  const int b = blockIdx.x;
  const int d = threadIdx.x * 4;
  float4 a = {0.f, 0.f, 0.f, 0.f};
  #pragma unroll 8
  for (int s = 0; s < CSPLIT; ++s) {
    const float4 p = *(const float4*)(partial + ((size_t)s * BB + b) * DD + d);
    a.x += p.x; a.y += p.y; a.z += p.z; a.w += p.w;
  }
  *(float4*)(ctx + (size_t)b * DD + d) = a;
}

// ---------------------------------------------------------------------------
extern "C" void kernel_launch(void* const* d_in, const int* in_sizes, int n_in,
                              void* d_out, int out_size, void* d_ws, size_t ws_size,
                              hipStream_t stream) {
  const float* query  = (const float*)d_in[0];
  const float* values = (const float*)d_in[1];
  const float* W1     = (const float*)d_in[2];
  const float* b1     = (const float*)d_in[3];
  const float* W2     = (const float*)d_in[4];
  const float* b2     = (const float*)d_in[5];
  const float* V      = (const float*)d_in[6];
  // d_in[7] = bV: uniform score shift -> softmax-invariant, dropped.

  float* ctx  = (float*)d_out;             // [B,D]
  float* attn = (float*)d_out + BB * DD;   // [B,T,1]

  // ws: qb 64KB | score 256KB | w1a 512KB | partial 4MB
  float* qb           = (float*)d_ws;                        // [B,U] fp32
  float* score        = qb + BB * UU;                        // [B*T] fp32
  unsigned short* w1a = (unsigned short*)(score + BB * TT);  // 512KB blocked bf16
  float* partial      = (float*)(w1a + (size_t)UU * DD);     // [64][B][D] fp32

  pack_w1a_kernel<<<dim3(16, 4), 256, 0, stream>>>(W1, w1a);
  projq_kernel<<<dim3(BB, UU / 256), 256, 0, stream>>>(query, W2, b2, b1, qb);

  score_kernel<<<(BB * TT) / SBM, 512, 0, stream>>>(values, w1a, qb, V, score);

  softmax_kernel<<<BB, 256, 0, stream>>>(score, attn);

  context1_kernel<<<dim3(CSPLIT, BB), 128, 0, stream>>>(values, attn, partial);
  context2_kernel<<<BB, 128, 0, stream>>>(partial, ctx);
}